// Round 3
// baseline (132.829 us; speedup 1.0000x reference)
//
#include <hip/hip_runtime.h>
#include <hip/hip_bf16.h>

#define NB 8
#define SEQ 2048
#define HD 1024
#define DK 64

typedef __attribute__((ext_vector_type(4))) float f32x4;
typedef __attribute__((ext_vector_type(8))) short bf16x8;

__device__ __forceinline__ short f2bf(float f) {
    union { float f; unsigned u; } v; v.f = f;
    unsigned r = v.u + 0x7fffu + ((v.u >> 16) & 1u);
    return (short)(r >> 16);
}
__device__ __forceinline__ float bf2f(short s) {
    union { float f; unsigned u; } v; v.u = ((unsigned)(unsigned short)s) << 16;
    return v.f;
}
__device__ __forceinline__ bf16x8 pack8(f32x4 v0, f32x4 v1) {
    union { bf16x8 v; __hip_bfloat162 h[4]; } u;
    u.h[0] = __float22bfloat162_rn(make_float2(v0[0], v0[1]));
    u.h[1] = __float22bfloat162_rn(make_float2(v0[2], v0[3]));
    u.h[2] = __float22bfloat162_rn(make_float2(v1[0], v1[1]));
    u.h[3] = __float22bfloat162_rn(make_float2(v1[2], v1[3]));
    return u.v;
}

// ---------------- prep: W pack (blocks 0..767) + lengths (768..775) ----------------
// Wp[((((m*16+kb)*2+kh)*4+n)*64+lane)*8+j] = W_m[k][col], k=kb*64+kh*32+g*8+j, col=n*16+c
__global__ void prep_kernel(const unsigned* __restrict__ mask,
                            const float* __restrict__ Wq, const float* __restrict__ Wk,
                            const float* __restrict__ Wv,
                            int* __restrict__ lengths, short* __restrict__ Wp) {
    if (blockIdx.x < 768) {
        int idx = blockIdx.x * 256 + threadIdx.x;
        int j = idx & 7, lane = (idx >> 3) & 63, n = (idx >> 9) & 3;
        int kh = (idx >> 11) & 1, kb = (idx >> 12) & 15, m = idx >> 16;
        int g = lane >> 4, c = lane & 15;
        int k = kb * 64 + kh * 32 + g * 8 + j, col = n * 16 + c;
        const float* W = (m == 0) ? Wq : (m == 1) ? Wk : Wv;
        Wp[idx] = f2bf(W[(size_t)k * DK + col]);
        return;
    }
    __shared__ int sdet;
    __shared__ int scnt;
    int b = blockIdx.x - 768, t = threadIdx.x;
    if (t == 0) { sdet = 0; scnt = 0; }
    __syncthreads();
    int det = 0;
    for (int i = t; i < 4096; i += 256) {
        unsigned w = mask[i];
        if (w > 1u && w != 0x3F800000u) det = 1;
    }
    if (det) atomicOr(&sdet, 1);
    __syncthreads();
    int cnt = 0;
    if (sdet) {
        const unsigned char* m8 = (const unsigned char*)mask;
        for (int s = t; s < SEQ; s += 256) cnt += (m8[b * SEQ + s] == 0) ? 1 : 0;
    } else {
        for (int s = t; s < SEQ; s += 256) cnt += (mask[b * SEQ + s] == 0u) ? 1 : 0;
    }
    atomicAdd(&scnt, cnt);
    __syncthreads();
    if (t == 0) lengths[b] = scnt;
}

// ---------------- QKV projection: grid (3 matrices, 512 row-groups) ----------------
// block = 32 rows x 64 cols of ONE matrix; 4 waves split K=1024 into 256 each.
__global__ __launch_bounds__(256) void qkv_kernel(
    const float* __restrict__ x,
    const float* __restrict__ bq, const float* __restrict__ bk, const float* __restrict__ bv,
    const short* __restrict__ Wp,
    short* __restrict__ Q, short* __restrict__ K, short* __restrict__ Vt) {
    __shared__ float red[2][32][64];   // 16 KiB
    int t = threadIdx.x;
    int w = t >> 6, lane = t & 63;
    int g = lane >> 4, c = lane & 15;
    int m = blockIdx.x;        // matrix 0..2
    int r0 = blockIdx.y * 32;  // row group

    f32x4 z = {0.f, 0.f, 0.f, 0.f};
    f32x4 acc[2][4];
    #pragma unroll
    for (int fr = 0; fr < 2; fr++)
        #pragma unroll
        for (int n = 0; n < 4; n++) acc[fr][n] = z;

    #pragma unroll
    for (int kb = 0; kb < 4; kb++) {
        int kbg = w * 4 + kb;
        int koff = kbg * 64;
        bf16x8 a[2][2];
        #pragma unroll
        for (int fr = 0; fr < 2; fr++)
            #pragma unroll
            for (int kh = 0; kh < 2; kh++) {
                const float* p = x + (size_t)(r0 + fr * 16 + c) * HD + koff + kh * 32 + g * 8;
                a[fr][kh] = pack8(*(const f32x4*)p, *(const f32x4*)(p + 4));
            }
        #pragma unroll
        for (int kh = 0; kh < 2; kh++) {
            const short* bp = Wp + (size_t)(((m * 16 + kbg) * 2 + kh) * 4) * 512 + lane * 8;
            #pragma unroll
            for (int n = 0; n < 4; n++) {
                bf16x8 bfr = *(const bf16x8*)(bp + n * 512);
                #pragma unroll
                for (int fr = 0; fr < 2; fr++)
                    acc[fr][n] = __builtin_amdgcn_mfma_f32_16x16x32_bf16(a[fr][kh], bfr, acc[fr][n], 0, 0, 0);
            }
        }
    }
    // two-phase cross-wave reduction (waves: 0+=1, 2+=3, then 0+=2)
    if (w & 1) {
        #pragma unroll
        for (int fr = 0; fr < 2; fr++)
            #pragma unroll
            for (int n = 0; n < 4; n++)
                #pragma unroll
                for (int j = 0; j < 4; j++)
                    red[w >> 1][(fr * 4 + n) * 4 + j][lane] = acc[fr][n][j];
    }
    __syncthreads();
    if (!(w & 1)) {
        #pragma unroll
        for (int fr = 0; fr < 2; fr++)
            #pragma unroll
            for (int n = 0; n < 4; n++)
                #pragma unroll
                for (int j = 0; j < 4; j++)
                    acc[fr][n][j] += red[w >> 1][(fr * 4 + n) * 4 + j][lane];
    }
    __syncthreads();
    if (w == 2) {
        #pragma unroll
        for (int fr = 0; fr < 2; fr++)
            #pragma unroll
            for (int n = 0; n < 4; n++)
                #pragma unroll
                for (int j = 0; j < 4; j++)
                    red[0][(fr * 4 + n) * 4 + j][lane] = acc[fr][n][j];
    }
    __syncthreads();
    if (w == 0) {
        const float* bias = (m == 0) ? bq : (m == 1) ? bk : bv;
        float bsc = (m == 0) ? 0.125f : 1.f;
        #pragma unroll
        for (int fr = 0; fr < 2; fr++)
            #pragma unroll
            for (int n = 0; n < 4; n++) {
                int col = n * 16 + c;
                float bv_ = bias[col];
                #pragma unroll
                for (int j = 0; j < 4; j++) {
                    float s = (acc[fr][n][j] + red[0][(fr * 4 + n) * 4 + j][lane] + bv_) * bsc;
                    int row = r0 + fr * 16 + 4 * g + j;
                    if (m == 0)      Q[(size_t)row * DK + col] = f2bf(s);
                    else if (m == 1) K[(size_t)row * DK + col] = f2bf(s);
                    else {
                        int bb = row >> 11, si = row & (SEQ - 1);
                        Vt[(size_t)bb * DK * SEQ + (size_t)col * SEQ + si] = f2bf(s);
                    }
                }
            }
    }
}

// ---------------- flash attention partials ----------------
// 1 wave/block, 32 q-rows, split=256 keys, tile=64 keys (max 4 iters).
// qt descending with blockIdx so heavy blocks dispatch first.
__global__ __launch_bounds__(64) void attn_part(
    const short* __restrict__ Q, const short* __restrict__ K_, const short* __restrict__ Vt,
    const int* __restrict__ lengths,
    short* __restrict__ po, float* __restrict__ pm, float* __restrict__ pl) {
    int bid = blockIdx.x;
    int s = bid & 7;
    int qt = 63 - ((bid >> 3) & 63);
    int b = bid >> 9;
    int len = lengths[b];
    int qbase = qt * 32;
    if (qbase >= len) return;
    int kend = min(len, qbase + 32);
    int klo = s << 8;
    int khi = min(kend, klo + 256);
    if (klo >= khi) return;

    int lane = threadIdx.x;
    int g = lane >> 4, c = lane & 15;
    const short* Qb = Q + ((size_t)b * SEQ + qbase) * DK;
    const short* Kb = K_ + (size_t)b * SEQ * DK;
    const short* Vb = Vt + (size_t)b * DK * SEQ;

    bf16x8 qa[2][2];
    #pragma unroll
    for (int f = 0; f < 2; f++)
        #pragma unroll
        for (int kh = 0; kh < 2; kh++)
            qa[f][kh] = *(const bf16x8*)(Qb + (f * 16 + c) * DK + kh * 32 + g * 8);

    int rowcap[2][4];
    #pragma unroll
    for (int f = 0; f < 2; f++)
        #pragma unroll
        for (int j = 0; j < 4; j++)
            rowcap[f][j] = min(qbase + f * 16 + 4 * g + j, len - 1);

    f32x4 z = {0.f, 0.f, 0.f, 0.f};
    f32x4 acc[2][4];
    float m_r[2][4], l_r[2][4];
    #pragma unroll
    for (int f = 0; f < 2; f++) {
        #pragma unroll
        for (int n = 0; n < 4; n++) acc[f][n] = z;
        #pragma unroll
        for (int j = 0; j < 4; j++) { m_r[f][j] = -1e30f; l_r[f][j] = 0.f; }
    }

    __shared__ short plds[16][68];   // single wave: reused per frag, no barriers needed

    for (int kb = klo; kb < khi; kb += 64) {
        #pragma unroll
        for (int f = 0; f < 2; f++) {
            // QK^T for 64 keys
            f32x4 sf[4];
            #pragma unroll
            for (int kt = 0; kt < 4; kt++) {
                const short* kp = Kb + (size_t)(kb + kt * 16 + c) * DK + g * 8;
                bf16x8 k0 = *(const bf16x8*)kp;
                bf16x8 k1 = *(const bf16x8*)(kp + 32);
                f32x4 tt = __builtin_amdgcn_mfma_f32_16x16x32_bf16(qa[f][0], k0, z, 0, 0, 0);
                sf[kt] = __builtin_amdgcn_mfma_f32_16x16x32_bf16(qa[f][1], k1, tt, 0, 0, 0);
            }
            // mask (causal + padding folded into rowcap)
            #pragma unroll
            for (int kt = 0; kt < 4; kt++) {
                int key = kb + kt * 16 + c;
                #pragma unroll
                for (int j = 0; j < 4; j++)
                    if (key > rowcap[f][j]) sf[kt][j] = -1e30f;
            }
            // online softmax
            float tm[4], p[4][4], rs[4], sc[4];
            #pragma unroll
            for (int j = 0; j < 4; j++)
                tm[j] = fmaxf(fmaxf(sf[0][j], sf[1][j]), fmaxf(sf[2][j], sf[3][j]));
            #pragma unroll
            for (int d = 1; d < 16; d <<= 1)
                #pragma unroll
                for (int j = 0; j < 4; j++) tm[j] = fmaxf(tm[j], __shfl_xor(tm[j], d));
            #pragma unroll
            for (int j = 0; j < 4; j++) {
                float mn = fmaxf(m_r[f][j], tm[j]);
                sc[j] = __expf(m_r[f][j] - mn);
                m_r[f][j] = mn;
            }
            #pragma unroll
            for (int j = 0; j < 4; j++) {
                rs[j] = 0.f;
                #pragma unroll
                for (int kt = 0; kt < 4; kt++) {
                    p[kt][j] = __expf(sf[kt][j] - m_r[f][j]);
                    rs[j] += p[kt][j];
                }
            }
            #pragma unroll
            for (int d = 1; d < 16; d <<= 1)
                #pragma unroll
                for (int j = 0; j < 4; j++) rs[j] += __shfl_xor(rs[j], d);
            #pragma unroll
            for (int j = 0; j < 4; j++) l_r[f][j] = l_r[f][j] * sc[j] + rs[j];
            #pragma unroll
            for (int n = 0; n < 4; n++)
                #pragma unroll
                for (int j = 0; j < 4; j++) acc[f][n][j] *= sc[j];
            // P: D-layout -> LDS -> A-layout (wave-private, lockstep: no barrier)
            #pragma unroll
            for (int kt = 0; kt < 4; kt++)
                #pragma unroll
                for (int j = 0; j < 4; j++)
                    plds[4 * g + j][kt * 16 + c] = f2bf(p[kt][j]);
            bf16x8 pa0 = *(const bf16x8*)(&plds[c][g * 8]);
            bf16x8 pa1 = *(const bf16x8*)(&plds[c][32 + g * 8]);
            // PV
            #pragma unroll
            for (int n = 0; n < 4; n++) {
                const short* vp = Vb + (size_t)(n * 16 + c) * SEQ + kb + g * 8;
                bf16x8 v0 = *(const bf16x8*)vp;
                bf16x8 v1 = *(const bf16x8*)(vp + 32);
                acc[f][n] = __builtin_amdgcn_mfma_f32_16x16x32_bf16(pa0, v0, acc[f][n], 0, 0, 0);
                acc[f][n] = __builtin_amdgcn_mfma_f32_16x16x32_bf16(pa1, v1, acc[f][n], 0, 0, 0);
            }
        }
    }
    // write partials
    size_t slot = (size_t)(b * 64 + qt) * 8 + s;
    short* pob = po + slot * 2048;
    #pragma unroll
    for (int f = 0; f < 2; f++)
        #pragma unroll
        for (int n = 0; n < 4; n++)
            #pragma unroll
            for (int j = 0; j < 4; j++)
                pob[(f * 16 + 4 * g + j) * 64 + n * 16 + c] = f2bf(acc[f][n][j]);
    if (c == 0) {
        #pragma unroll
        for (int f = 0; f < 2; f++)
            #pragma unroll
            for (int j = 0; j < 4; j++) {
                int row = f * 16 + 4 * g + j;
                pm[slot * 32 + row] = m_r[f][j];
                pl[slot * 32 + row] = l_r[f][j];
            }
    }
}

// ---------------- combine partials ----------------
__global__ __launch_bounds__(256) void attn_combine(
    const short* __restrict__ po, const float* __restrict__ pm, const float* __restrict__ pl,
    const int* __restrict__ lengths, float* __restrict__ out) {
    int blk = blockIdx.x;               // NB*64 q-tiles
    int b = blk >> 6, qt = blk & 63;
    int qbase = qt * 32;
    int len = lengths[b];
    int kend = min(len, qbase + 32);
    int t = threadIdx.x;
    int lane = t & 63, rq = t >> 6;
    int nact = (qbase >= len) ? 0 : ((kend + 255) >> 8);
    float* ob = out + ((size_t)b * SEQ + qbase) * DK;
    for (int row = rq; row < 32; row += 4) {
        int r = qbase + row;
        float val = 0.f;
        if (r < len) {
            float M = -1e30f;
            for (int s2 = 0; s2 < nact; s2++) M = fmaxf(M, pm[(size_t)(blk * 8 + s2) * 32 + row]);
            float L = 0.f, a = 0.f;
            for (int s2 = 0; s2 < nact; s2++) {
                size_t pidx = (size_t)(blk * 8 + s2) * 32 + row;
                float wgt = __expf(pm[pidx] - M);
                L += wgt * pl[pidx];
                a += wgt * bf2f(po[pidx * 64 + lane]);
            }
            val = a / L;
        }
        ob[(size_t)row * DK + lane] = val;
    }
}

extern "C" void kernel_launch(void* const* d_in, const int* in_sizes, int n_in,
                              void* d_out, int out_size, void* d_ws, size_t ws_size,
                              hipStream_t stream) {
    const float* x  = (const float*)d_in[0];
    const unsigned* mask = (const unsigned*)d_in[1];
    const float* Wq = (const float*)d_in[2];
    const float* bq = (const float*)d_in[3];
    const float* Wk = (const float*)d_in[4];
    const float* bk = (const float*)d_in[5];
    const float* Wv = (const float*)d_in[6];
    const float* bv = (const float*)d_in[7];
    float* out = (float*)d_out;

    char* ws = (char*)d_ws;
    int*   lengths = (int*)ws;                          // 256 B
    short* Wp = (short*)(ws + 256);                     // 384 KiB
    short* Q  = (short*)(ws + 393472);                  // 2 MiB
    short* K  = (short*)(ws + 2490624);                 // 2 MiB
    short* Vt = (short*)(ws + 4587776);                 // 2 MiB
    short* po = (short*)(ws + 6684928);                 // 16 MiB (4096 slots * 32 * 64 bf16)
    float* pm = (float*)(ws + 23462144);                // 512 KiB
    float* pl = (float*)(ws + 23986432);                // 512 KiB -> total ~24.5 MiB

    hipLaunchKernelGGL(prep_kernel, dim3(776), dim3(256), 0, stream, mask, Wq, Wk, Wv, lengths, Wp);
    hipLaunchKernelGGL(qkv_kernel, dim3(3, 512), dim3(256), 0, stream,
                       x, bq, bk, bv, Wp, Q, K, Vt);
    hipLaunchKernelGGL(attn_part, dim3(NB * 64 * 8), dim3(64), 0, stream,
                       Q, K, Vt, lengths, po, pm, pl);
    hipLaunchKernelGGL(attn_combine, dim3(NB * 64), dim3(256), 0, stream,
                       po, pm, pl, lengths, out);
}

// Round 4
// 85.065 us; speedup vs baseline: 1.5615x; 1.5615x over previous
//
#include <hip/hip_runtime.h>
#include <hip/hip_bf16.h>

#define NB 8
#define SEQ 2048
#define HD 1024
#define DK 64

typedef __attribute__((ext_vector_type(4))) float f32x4;
typedef __attribute__((ext_vector_type(8))) short bf16x8;

__device__ __forceinline__ short f2bf(float f) {
    union { float f; unsigned u; } v; v.f = f;
    unsigned r = v.u + 0x7fffu + ((v.u >> 16) & 1u);
    return (short)(r >> 16);
}
__device__ __forceinline__ bf16x8 pack8(f32x4 v0, f32x4 v1) {
    union { bf16x8 v; __hip_bfloat162 h[4]; } u;
    u.h[0] = __float22bfloat162_rn(make_float2(v0[0], v0[1]));
    u.h[1] = __float22bfloat162_rn(make_float2(v0[2], v0[3]));
    u.h[2] = __float22bfloat162_rn(make_float2(v1[0], v1[1]));
    u.h[3] = __float22bfloat162_rn(make_float2(v1[2], v1[3]));
    return u.v;
}

// ---------------- prep: W pack (blocks 0..767) + lengths (768..775) ----------------
__global__ void prep_kernel(const unsigned* __restrict__ mask,
                            const float* __restrict__ Wq, const float* __restrict__ Wk,
                            const float* __restrict__ Wv,
                            int* __restrict__ lengths, short* __restrict__ Wp) {
    if (blockIdx.x < 768) {
        int idx = blockIdx.x * 256 + threadIdx.x;
        int j = idx & 7, lane = (idx >> 3) & 63, n = (idx >> 9) & 3;
        int kh = (idx >> 11) & 1, kb = (idx >> 12) & 15, m = idx >> 16;
        int g = lane >> 4, c = lane & 15;
        int k = kb * 64 + kh * 32 + g * 8 + j, col = n * 16 + c;
        const float* W = (m == 0) ? Wq : (m == 1) ? Wk : Wv;
        Wp[idx] = f2bf(W[(size_t)k * DK + col]);
        return;
    }
    __shared__ int sdet;
    __shared__ int scnt;
    int b = blockIdx.x - 768, t = threadIdx.x;
    if (t == 0) { sdet = 0; scnt = 0; }
    __syncthreads();
    int det = 0;
    for (int i = t; i < 4096; i += 256) {
        unsigned w = mask[i];
        if (w > 1u && w != 0x3F800000u) det = 1;
    }
    if (det) atomicOr(&sdet, 1);
    __syncthreads();
    int cnt = 0;
    if (sdet) {
        const unsigned char* m8 = (const unsigned char*)mask;
        for (int s = t; s < SEQ; s += 256) cnt += (m8[b * SEQ + s] == 0) ? 1 : 0;
    } else {
        for (int s = t; s < SEQ; s += 256) cnt += (mask[b * SEQ + s] == 0u) ? 1 : 0;
    }
    atomicAdd(&scnt, cnt);
    __syncthreads();
    if (t == 0) lengths[b] = scnt;
}

// ---------------- QKV projection: block = 16 rows, ALL 3 matrices, 4-wave K-split ----
__global__ __launch_bounds__(256) void qkv_kernel(
    const float* __restrict__ x,
    const float* __restrict__ bq, const float* __restrict__ bk, const float* __restrict__ bv,
    const short* __restrict__ Wp,
    short* __restrict__ Q, short* __restrict__ K, short* __restrict__ Vt) {
    __shared__ float red[4][48][66];   // 50.7 KiB
    int t = threadIdx.x;
    int w = t >> 6, lane = t & 63;
    int g = lane >> 4, c = lane & 15;
    int r0 = blockIdx.x * 16;

    f32x4 z = {0.f, 0.f, 0.f, 0.f};
    f32x4 acc[3][4];
    #pragma unroll
    for (int m = 0; m < 3; m++)
        #pragma unroll
        for (int n = 0; n < 4; n++) acc[m][n] = z;

    const float* xr = x + (size_t)(r0 + c) * HD + w * 256;
    #pragma unroll
    for (int kb = 0; kb < 4; kb++) {
        int kbg = w * 4 + kb;
        bf16x8 a[2];
        #pragma unroll
        for (int kh = 0; kh < 2; kh++) {
            const float* p = xr + kb * 64 + kh * 32 + g * 8;
            a[kh] = pack8(*(const f32x4*)p, *(const f32x4*)(p + 4));
        }
        #pragma unroll
        for (int m = 0; m < 3; m++)
            #pragma unroll
            for (int kh = 0; kh < 2; kh++) {
                const short* bp = Wp + (size_t)(((m * 16 + kbg) * 2 + kh) * 4) * 512 + lane * 8;
                #pragma unroll
                for (int n = 0; n < 4; n++) {
                    bf16x8 bfr = *(const bf16x8*)(bp + n * 512);
                    acc[m][n] = __builtin_amdgcn_mfma_f32_16x16x32_bf16(a[kh], bfr, acc[m][n], 0, 0, 0);
                }
            }
    }
    // dump all 4 waves' partials, then all-thread reduce + epilogue
    #pragma unroll
    for (int m = 0; m < 3; m++)
        #pragma unroll
        for (int n = 0; n < 4; n++)
            #pragma unroll
            for (int j = 0; j < 4; j++)
                red[w][(m * 4 + n) * 4 + j][lane] = acc[m][n][j];
    __syncthreads();
    #pragma unroll
    for (int oi = 0; oi < 12; oi++) {
        int idx = oi * 256 + t;
        int i = idx >> 6, l = idx & 63;
        float s = red[0][i][l] + red[1][i][l] + red[2][i][l] + red[3][i][l];
        int m = i >> 4, n = (i >> 2) & 3, j = i & 3;
        int gg = l >> 4, cc = l & 15;
        int row = r0 + 4 * gg + j, col = n * 16 + cc;
        if (m == 0)      Q[(size_t)row * DK + col] = f2bf((s + bq[col]) * 0.125f);
        else if (m == 1) K[(size_t)row * DK + col] = f2bf(s + bk[col]);
        else {
            int bb = row >> 11, si = row & (SEQ - 1);
            Vt[(size_t)bb * DK * SEQ + (size_t)col * SEQ + si] = f2bf(s + bv[col]);
        }
    }
}

// ---------------- flash attention: block = one 32-row q-tile, 4 waves split keys ----
// Wave w handles 64-key tiles tt = w, w+4, ... (interleaved => balanced).
// Block-local merge of the 4 online-softmax partials through LDS. No global partials.
__global__ __launch_bounds__(256, 3) void attn_kernel(
    const short* __restrict__ Q, const short* __restrict__ K_, const short* __restrict__ Vt,
    const int* __restrict__ lengths, float* __restrict__ out) {
    __shared__ float macc[4][32][66];          // merge buffer (33.8 KiB)
    __shared__ float lm[4][32], ll[4][32];
    short* plds = (short*)&macc[0][0][0];      // aliased P-transpose region (17.9 KiB)

    int bid = blockIdx.x;
    int qt = 63 - (bid & 63);                  // heavy tiles dispatch first
    int b = bid >> 6;
    int len = lengths[b];
    int qbase = qt * 32;
    int t = threadIdx.x;
    int w = t >> 6, lane = t & 63;
    int g = lane >> 4, c = lane & 15;

    if (qbase >= len) {                        // fully padded tile -> zeros
        int row = t >> 3, seg = t & 7;
        float* op = out + ((size_t)b * SEQ + qbase + row) * DK + seg * 8;
        #pragma unroll
        for (int i = 0; i < 8; i++) op[i] = 0.f;
        return;
    }

    int kend = min(len, qbase + 32);
    int ntiles = (kend + 63) >> 6;
    const short* Qb = Q + ((size_t)b * SEQ + qbase) * DK;
    const short* Kb = K_ + (size_t)b * SEQ * DK;
    const short* Vb = Vt + (size_t)b * DK * SEQ;

    bf16x8 qa[2][2];
    #pragma unroll
    for (int f = 0; f < 2; f++)
        #pragma unroll
        for (int kh = 0; kh < 2; kh++)
            qa[f][kh] = *(const bf16x8*)(Qb + (f * 16 + c) * DK + kh * 32 + g * 8);

    f32x4 z = {0.f, 0.f, 0.f, 0.f};
    f32x4 acc[2][4];
    float m_r[2][4], l_r[2][4];
    #pragma unroll
    for (int f = 0; f < 2; f++) {
        #pragma unroll
        for (int n = 0; n < 4; n++) acc[f][n] = z;
        #pragma unroll
        for (int j = 0; j < 4; j++) { m_r[f][j] = -1e30f; l_r[f][j] = 0.f; }
    }

    short* pldsw = plds + w * 2240;            // [2][16][70] shorts per wave

    for (int tt = w; tt < ntiles; tt += 4) {
        int kb = tt * 64;
        // QK^T: 64 keys, both frags interleaved (kt halves to bound K regs)
        f32x4 sf[2][4];
        #pragma unroll
        for (int kp2 = 0; kp2 < 2; kp2++) {
            bf16x8 kr[2][2];
            #pragma unroll
            for (int kt = 0; kt < 2; kt++) {
                const short* kp = Kb + (size_t)(kb + (kp2 * 2 + kt) * 16 + c) * DK + g * 8;
                kr[kt][0] = *(const bf16x8*)kp;
                kr[kt][1] = *(const bf16x8*)(kp + 32);
            }
            #pragma unroll
            for (int kt = 0; kt < 2; kt++)
                #pragma unroll
                for (int f = 0; f < 2; f++) {
                    f32x4 t0 = __builtin_amdgcn_mfma_f32_16x16x32_bf16(qa[f][0], kr[kt][0], z, 0, 0, 0);
                    sf[f][kp2 * 2 + kt] = __builtin_amdgcn_mfma_f32_16x16x32_bf16(qa[f][1], kr[kt][1], t0, 0, 0, 0);
                }
        }
        // V loads issued early (independent of softmax chain)
        bf16x8 vr[4][2];
        #pragma unroll
        for (int n = 0; n < 4; n++) {
            const short* vp = Vb + (size_t)(n * 16 + c) * SEQ + kb + g * 8;
            vr[n][0] = *(const bf16x8*)vp;
            vr[n][1] = *(const bf16x8*)(vp + 32);
        }
        // causal+padding mask (rowcap = min(row, len-1))
        #pragma unroll
        for (int kt = 0; kt < 4; kt++) {
            int key = kb + kt * 16 + c;
            #pragma unroll
            for (int f = 0; f < 2; f++)
                #pragma unroll
                for (int j = 0; j < 4; j++)
                    if (key > min(qbase + f * 16 + 4 * g + j, len - 1)) sf[f][kt][j] = -1e30f;
        }
        // online softmax, both frags interleaved
        float tm[2][4], sc[2][4], rs[2][4];
        #pragma unroll
        for (int f = 0; f < 2; f++)
            #pragma unroll
            for (int j = 0; j < 4; j++)
                tm[f][j] = fmaxf(fmaxf(sf[f][0][j], sf[f][1][j]), fmaxf(sf[f][2][j], sf[f][3][j]));
        #pragma unroll
        for (int d = 1; d < 16; d <<= 1)
            #pragma unroll
            for (int f = 0; f < 2; f++)
                #pragma unroll
                for (int j = 0; j < 4; j++) tm[f][j] = fmaxf(tm[f][j], __shfl_xor(tm[f][j], d));
        #pragma unroll
        for (int f = 0; f < 2; f++)
            #pragma unroll
            for (int j = 0; j < 4; j++) {
                float mn = fmaxf(m_r[f][j], tm[f][j]);
                sc[f][j] = __expf(m_r[f][j] - mn);
                m_r[f][j] = mn;
            }
        #pragma unroll
        for (int f = 0; f < 2; f++)
            #pragma unroll
            for (int j = 0; j < 4; j++) {
                rs[f][j] = 0.f;
                #pragma unroll
                for (int kt = 0; kt < 4; kt++) {
                    float p = __expf(sf[f][kt][j] - m_r[f][j]);
                    sf[f][kt][j] = p;
                    rs[f][j] += p;
                }
            }
        #pragma unroll
        for (int d = 1; d < 16; d <<= 1)
            #pragma unroll
            for (int f = 0; f < 2; f++)
                #pragma unroll
                for (int j = 0; j < 4; j++) rs[f][j] += __shfl_xor(rs[f][j], d);
        #pragma unroll
        for (int f = 0; f < 2; f++) {
            #pragma unroll
            for (int j = 0; j < 4; j++) l_r[f][j] = l_r[f][j] * sc[f][j] + rs[f][j];
            #pragma unroll
            for (int n = 0; n < 4; n++)
                #pragma unroll
                for (int j = 0; j < 4; j++) acc[f][n][j] *= sc[f][j];
        }
        // P: D-layout -> LDS -> A-layout (wave-private lockstep, no barrier)
        #pragma unroll
        for (int f = 0; f < 2; f++)
            #pragma unroll
            for (int kt = 0; kt < 4; kt++)
                #pragma unroll
                for (int j = 0; j < 4; j++)
                    pldsw[f * 1120 + (4 * g + j) * 70 + kt * 16 + c] = f2bf(sf[f][kt][j]);
        #pragma unroll
        for (int f = 0; f < 2; f++) {
            bf16x8 pa0 = *(const bf16x8*)(pldsw + f * 1120 + c * 70 + g * 8);
            bf16x8 pa1 = *(const bf16x8*)(pldsw + f * 1120 + c * 70 + 32 + g * 8);
            #pragma unroll
            for (int n = 0; n < 4; n++) {
                acc[f][n] = __builtin_amdgcn_mfma_f32_16x16x32_bf16(pa0, vr[n][0], acc[f][n], 0, 0, 0);
                acc[f][n] = __builtin_amdgcn_mfma_f32_16x16x32_bf16(pa1, vr[n][1], acc[f][n], 0, 0, 0);
            }
        }
    }

    __syncthreads();   // all waves done with plds region -> safe to reuse as macc
    #pragma unroll
    for (int f = 0; f < 2; f++)
        #pragma unroll
        for (int n = 0; n < 4; n++)
            #pragma unroll
            for (int j = 0; j < 4; j++)
                macc[w][f * 16 + 4 * g + j][n * 16 + c] = acc[f][n][j];
    if (c == 0) {
        #pragma unroll
        for (int f = 0; f < 2; f++)
            #pragma unroll
            for (int j = 0; j < 4; j++) {
                lm[w][f * 16 + 4 * g + j] = m_r[f][j];
                ll[w][f * 16 + 4 * g + j] = l_r[f][j];
            }
    }
    __syncthreads();
    // merge 4 wave-partials, normalize, store f32
    {
        int row = t >> 3, seg = t & 7;
        int r = qbase + row;
        float* op = out + ((size_t)b * SEQ + r) * DK + seg * 8;
        float o[8];
        #pragma unroll
        for (int i = 0; i < 8; i++) o[i] = 0.f;
        if (r < len) {
            float M = fmaxf(fmaxf(lm[0][row], lm[1][row]), fmaxf(lm[2][row], lm[3][row]));
            float L = 0.f;
            #pragma unroll
            for (int wv = 0; wv < 4; wv++) {
                float wgt = __expf(lm[wv][row] - M);
                L += wgt * ll[wv][row];
                #pragma unroll
                for (int i = 0; i < 8; i++) o[i] += wgt * macc[wv][row][seg * 8 + i];
            }
            float inv = 1.f / L;
            #pragma unroll
            for (int i = 0; i < 8; i++) o[i] *= inv;
        }
        #pragma unroll
        for (int i = 0; i < 8; i++) op[i] = o[i];
    }
}

extern "C" void kernel_launch(void* const* d_in, const int* in_sizes, int n_in,
                              void* d_out, int out_size, void* d_ws, size_t ws_size,
                              hipStream_t stream) {
    const float* x  = (const float*)d_in[0];
    const unsigned* mask = (const unsigned*)d_in[1];
    const float* Wq = (const float*)d_in[2];
    const float* bq = (const float*)d_in[3];
    const float* Wk = (const float*)d_in[4];
    const float* bk = (const float*)d_in[5];
    const float* Wv = (const float*)d_in[6];
    const float* bv = (const float*)d_in[7];
    float* out = (float*)d_out;

    char* ws = (char*)d_ws;
    int*   lengths = (int*)ws;                          // 256 B
    short* Wp = (short*)(ws + 256);                     // 384 KiB
    short* Q  = (short*)(ws + 393472);                  // 2 MiB
    short* K  = (short*)(ws + 2490624);                 // 2 MiB
    short* Vt = (short*)(ws + 4587776);                 // 2 MiB

    hipLaunchKernelGGL(prep_kernel, dim3(776), dim3(256), 0, stream, mask, Wq, Wk, Wv, lengths, Wp);
    hipLaunchKernelGGL(qkv_kernel, dim3(NB * SEQ / 16), dim3(256), 0, stream,
                       x, bq, bk, bv, Wp, Q, K, Vt);
    hipLaunchKernelGGL(attn_kernel, dim3(NB * 64), dim3(256), 0, stream,
                       Q, K, Vt, lengths, out);
}